// Round 3
// baseline (6897.036 us; speedup 1.0000x reference)
//
#include <hip/hip_runtime.h>

#define B_ 64
#define S_ 512
#define I_ 1024
#define H_ 1024
#define G_ 4096   // 4*H
#define NB 64     // persistent blocks
#define WPAD 1032 // LDS row stride in ushort (2064B = 516 dwords -> 2-way alias, free)

typedef __attribute__((ext_vector_type(4))) float f32x4;
typedef __attribute__((ext_vector_type(8))) short bf16x8;

static __device__ __forceinline__ ushort f2b(float f) {
    union { float f; unsigned u; } v; v.f = f;
    unsigned u = v.u;
    unsigned r = (u + 0x7fffu + ((u >> 16) & 1u)) >> 16;
    return (ushort)r;
}
static __device__ __forceinline__ float b2f(ushort b) {
    union { unsigned u; float f; } v; v.u = ((unsigned)b) << 16; return v.f;
}

// ---------------------------------------------------------------------------
// fp32 -> bf16 conversion, vectorized
// ---------------------------------------------------------------------------
__global__ __launch_bounds__(256) void conv_f2b_kernel(
    const float* __restrict__ in, ushort* __restrict__ out, int n4)
{
    int i = blockIdx.x * blockDim.x + threadIdx.x;
    int stride = gridDim.x * blockDim.x;
    for (; i < n4; i += stride) {
        float4 v = ((const float4*)in)[i];
        ushort4 o;
        o.x = f2b(v.x); o.y = f2b(v.y); o.z = f2b(v.z); o.w = f2b(v.w);
        ((ushort4*)out)[i] = o;
    }
}

// ---------------------------------------------------------------------------
// x-projection GEMM (bf16 MFMA): xp[s][b][4H] = X[M=b*S+s][I] @ W_ih^T + biases
// BM=BN=128, BK=32, 4 waves 2x2, 64x64 per wave. xp stored bf16, [S][B][4H].
// ---------------------------------------------------------------------------
__global__ __launch_bounds__(256) void xproj_mfma(
    const ushort* __restrict__ Xb, const ushort* __restrict__ Wb,
    const float* __restrict__ bih, const float* __restrict__ bhh,
    ushort* __restrict__ xp)
{
    __shared__ ushort As[128][40];
    __shared__ ushort Bs[128][40];
    const int tid  = threadIdx.x;
    const int lane = tid & 63;
    const int w    = tid >> 6;
    const int wm   = (w >> 1) * 64, wn = (w & 1) * 64;
    const int m0   = blockIdx.y * 128, n0 = blockIdx.x * 128;

    const int srow   = tid >> 2;
    const int schunk = (tid & 3) * 8;

    const ushort* Xr0 = Xb + (size_t)(m0 + srow) * I_ + schunk;
    const ushort* Xr1 = Xb + (size_t)(m0 + srow + 64) * I_ + schunk;
    const ushort* Wr0 = Wb + (size_t)(n0 + srow) * I_ + schunk;
    const ushort* Wr1 = Wb + (size_t)(n0 + srow + 64) * I_ + schunk;

    f32x4 acc[4][4];
#pragma unroll
    for (int mi = 0; mi < 4; ++mi)
#pragma unroll
        for (int ni = 0; ni < 4; ++ni)
#pragma unroll
            for (int r = 0; r < 4; ++r) acc[mi][ni][r] = 0.f;

    bf16x8 ra0 = *(const bf16x8*)Xr0;
    bf16x8 ra1 = *(const bf16x8*)Xr1;
    bf16x8 rb0 = *(const bf16x8*)Wr0;
    bf16x8 rb1 = *(const bf16x8*)Wr1;

    const int arow = lane & 15;
    const int akg  = (lane >> 4) * 8;

    for (int kt = 0; kt < 32; ++kt) {
        __syncthreads();
        *(bf16x8*)&As[srow][schunk]      = ra0;
        *(bf16x8*)&As[srow + 64][schunk] = ra1;
        *(bf16x8*)&Bs[srow][schunk]      = rb0;
        *(bf16x8*)&Bs[srow + 64][schunk] = rb1;
        __syncthreads();
        if (kt < 31) {
            int k0 = (kt + 1) * 32;
            ra0 = *(const bf16x8*)(Xr0 + k0);
            ra1 = *(const bf16x8*)(Xr1 + k0);
            rb0 = *(const bf16x8*)(Wr0 + k0);
            rb1 = *(const bf16x8*)(Wr1 + k0);
        }
        bf16x8 af[4], bfv[4];
#pragma unroll
        for (int mi = 0; mi < 4; ++mi)
            af[mi] = *(const bf16x8*)&As[wm + mi * 16 + arow][akg];
#pragma unroll
        for (int ni = 0; ni < 4; ++ni)
            bfv[ni] = *(const bf16x8*)&Bs[wn + ni * 16 + arow][akg];
#pragma unroll
        for (int mi = 0; mi < 4; ++mi)
#pragma unroll
            for (int ni = 0; ni < 4; ++ni)
                acc[mi][ni] = __builtin_amdgcn_mfma_f32_16x16x32_bf16(
                    af[mi], bfv[ni], acc[mi][ni], 0, 0, 0);
    }

    float bsum[4];
#pragma unroll
    for (int ni = 0; ni < 4; ++ni) {
        int col = n0 + wn + ni * 16 + (lane & 15);
        bsum[ni] = bih[col] + bhh[col];
    }
#pragma unroll
    for (int mi = 0; mi < 4; ++mi)
#pragma unroll
        for (int ni = 0; ni < 4; ++ni) {
            int col = n0 + wn + ni * 16 + (lane & 15);
#pragma unroll
            for (int r = 0; r < 4; ++r) {
                int row = m0 + wm + mi * 16 + (lane >> 4) * 4 + r;  // = b*S + s
                int bb = row >> 9, ss = row & 511;
                xp[(size_t)(ss * B_ + bb) * G_ + col] = f2b(acc[mi][ni][r] + bsum[ni]);
            }
        }
}

// ---------------------------------------------------------------------------
// Persistent LSTM recurrence: 64 blocks, all 512 steps in one launch.
// Block = 16 h-cols x 4 gates (64 W rows in LDS, persistent). Wave w = batch
// rows 16w..16w+15. Lane-local epilogue: acc[g][r] holds gate g preact for
// (row = m0+kg*4+r, col = c0+l15). c-state lives in registers all 512 steps.
// Grid barrier: device-scope atomics + agent fences (cross-XCD safe).
// ---------------------------------------------------------------------------
__global__ __launch_bounds__(256, 1) void lstm_persist(
    const ushort* __restrict__ Whhb, const ushort* __restrict__ xp,
    ushort* __restrict__ hb0, ushort* __restrict__ hb1,
    float* __restrict__ hseq, float* __restrict__ hlast,
    float* __restrict__ clast, int* __restrict__ cnt)
{
    __shared__ ushort Ws[64 * WPAD];  // 132096 B

    const int tid  = threadIdx.x;
    const int lane = tid & 63;
    const int w    = tid >> 6;
    const int c0   = blockIdx.x * 16;
    const int l15  = lane & 15;
    const int kg   = lane >> 4;
    const int m0   = w * 16;

    // Load W slice: LDS row r = g*16+cc  <-  Whh row g*1024 + c0 + cc
#pragma unroll
    for (int i = 0; i < 32; ++i) {
        int id = tid + 256 * i;
        int r  = id >> 7;
        int k8 = (id & 127) * 8;
        int g = r >> 4, cc = r & 15;
        *(bf16x8*)&Ws[r * WPAD + k8] =
            *(const bf16x8*)(Whhb + (size_t)(g * H_ + c0 + cc) * H_ + k8);
    }

    float creg[4] = {0.f, 0.f, 0.f, 0.f};
    __syncthreads();

    for (int s = 0; s < S_; ++s) {
        const ushort* hp = (s & 1) ? hb1 : hb0;
        ushort*       hn = (s & 1) ? hb0 : hb1;

        // xp prefetch for this step (HBM slab [s][.][.]), issued first
        ushort xu[4][4];
        const size_t xbase = (size_t)s * B_ * G_ + c0 + l15;
#pragma unroll
        for (int r = 0; r < 4; ++r)
#pragma unroll
            for (int g = 0; g < 4; ++g)
                xu[r][g] = xp[xbase + (size_t)(m0 + kg * 4 + r) * G_ + g * H_];

        // A fragments: h rows m0+l15, all K (L2/L3-resident)
        const ushort* Ap = hp + (size_t)(m0 + l15) * H_ + kg * 8;
        bf16x8 a[32];
#pragma unroll
        for (int u = 0; u < 32; ++u) a[u] = *(const bf16x8*)(Ap + u * 32);

        f32x4 ac0, ac1, ac2, ac3;
#pragma unroll
        for (int r = 0; r < 4; ++r) { ac0[r] = 0.f; ac1[r] = 0.f; ac2[r] = 0.f; ac3[r] = 0.f; }

#pragma unroll
        for (int u = 0; u < 32; ++u) {
            const ushort* wp = &Ws[l15 * WPAD + u * 32 + kg * 8];
            bf16x8 b0 = *(const bf16x8*)(wp);
            bf16x8 b1 = *(const bf16x8*)(wp + 16 * WPAD);
            bf16x8 b2 = *(const bf16x8*)(wp + 32 * WPAD);
            bf16x8 b3 = *(const bf16x8*)(wp + 48 * WPAD);
            ac0 = __builtin_amdgcn_mfma_f32_16x16x32_bf16(a[u], b0, ac0, 0, 0, 0);
            ac1 = __builtin_amdgcn_mfma_f32_16x16x32_bf16(a[u], b1, ac1, 0, 0, 0);
            ac2 = __builtin_amdgcn_mfma_f32_16x16x32_bf16(a[u], b2, ac2, 0, 0, 0);
            ac3 = __builtin_amdgcn_mfma_f32_16x16x32_bf16(a[u], b3, ac3, 0, 0, 0);
        }

        // lane-local epilogue
#pragma unroll
        for (int r = 0; r < 4; ++r) {
            int bb = m0 + kg * 4 + r;
            float gi = ac0[r] + b2f(xu[r][0]);
            float gf = ac1[r] + b2f(xu[r][1]);
            float gg = ac2[r] + b2f(xu[r][2]);
            float go = ac3[r] + b2f(xu[r][3]);
            float ii = 1.f / (1.f + __expf(-gi));
            float ff = 1.f / (1.f + __expf(-gf));
            float gt = 1.f - 2.f / (__expf(2.f * gg) + 1.f);
            float oo = 1.f / (1.f + __expf(-go));
            float cn = ff * creg[r] + ii * gt;
            float hv = oo * (1.f - 2.f / (__expf(2.f * cn) + 1.f));
            creg[r] = cn;
            size_t hidx = (size_t)bb * H_ + c0 + l15;
            hn[hidx] = f2b(hv);
            hseq[((size_t)bb * S_ + s) * H_ + c0 + l15] = hv;
            if (s == S_ - 1) {
                hlast[hidx] = hv;
                clast[hidx] = cn;
            }
        }

        // grid barrier (skip after last step)
        if (s < S_ - 1) {
            __syncthreads();  // drains vmcnt: all block h-stores issued & complete
            if (tid == 0) {
                __builtin_amdgcn_fence(__ATOMIC_RELEASE, "agent");
                __hip_atomic_fetch_add(cnt, 1, __ATOMIC_RELAXED, __HIP_MEMORY_SCOPE_AGENT);
                int target = NB * (s + 1);
                while (__hip_atomic_load(cnt, __ATOMIC_RELAXED, __HIP_MEMORY_SCOPE_AGENT) < target)
                    __builtin_amdgcn_s_sleep(2);
            }
            __syncthreads();
            __builtin_amdgcn_fence(__ATOMIC_ACQUIRE, "agent");
        }
    }
}

extern "C" void kernel_launch(void* const* d_in, const int* in_sizes, int n_in,
                              void* d_out, int out_size, void* d_ws, size_t ws_size,
                              hipStream_t stream) {
    const float* x   = (const float*)d_in[0];
    const float* Wih = (const float*)d_in[1];
    const float* Whh = (const float*)d_in[2];
    const float* bih = (const float*)d_in[3];
    const float* bhh = (const float*)d_in[4];
    float* out = (float*)d_out;

    // workspace layout (ushort elems)
    ushort* xp   = (ushort*)d_ws;           // 134217728 (268 MB), [S][B][4H]
    ushort* xbf  = xp + 134217728;          // 33554432
    ushort* wihb = xbf + 33554432;          // 4194304
    ushort* whhb = wihb + 4194304;          // 4194304
    ushort* hb0  = whhb + 4194304;          // 65536
    ushort* hb1  = hb0 + 65536;             // 65536
    int*    cnt  = (int*)(hb1 + 65536);

    float* hseq  = out;
    float* hlast = out + (size_t)B_ * S_ * H_;
    float* clast = hlast + (size_t)B_ * H_;

    hipMemsetAsync(hb0, 0, (size_t)B_ * H_ * sizeof(ushort), stream);
    hipMemsetAsync(cnt, 0, 64, stream);

    conv_f2b_kernel<<<2048, 256, 0, stream>>>(x, xbf, (B_ * S_ * I_) / 4);
    conv_f2b_kernel<<<1024, 256, 0, stream>>>(Wih, wihb, (G_ * I_) / 4);
    conv_f2b_kernel<<<1024, 256, 0, stream>>>(Whh, whhb, (G_ * H_) / 4);

    dim3 gg(G_ / 128, (B_ * S_) / 128);
    xproj_mfma<<<gg, 256, 0, stream>>>(xbf, wihb, bih, bhh, xp);

    lstm_persist<<<NB, 256, 0, stream>>>(whhb, xp, hb0, hb1,
                                         hseq, hlast, clast, cnt);
}

// Round 4
// 5804.922 us; speedup vs baseline: 1.1881x; 1.1881x over previous
//
#include <hip/hip_runtime.h>

#define B_ 64
#define S_ 512
#define I_ 1024
#define H_ 1024
#define G_ 4096   // 4*H
#define NB 64     // persistent blocks
#define WPAD 1032 // LDS row stride in ushort

typedef __attribute__((ext_vector_type(4))) float f32x4;
typedef __attribute__((ext_vector_type(8))) short bf16x8;

static __device__ __forceinline__ ushort f2b(float f) {
    union { float f; unsigned u; } v; v.f = f;
    unsigned u = v.u;
    unsigned r = (u + 0x7fffu + ((u >> 16) & 1u)) >> 16;
    return (ushort)r;
}
static __device__ __forceinline__ float b2f(ushort b) {
    union { unsigned u; float f; } v; v.u = ((unsigned)b) << 16; return v.f;
}

// ---------------------------------------------------------------------------
// fp32 -> bf16 conversion, vectorized
// ---------------------------------------------------------------------------
__global__ __launch_bounds__(256) void conv_f2b_kernel(
    const float* __restrict__ in, ushort* __restrict__ out, int n4)
{
    int i = blockIdx.x * blockDim.x + threadIdx.x;
    int stride = gridDim.x * blockDim.x;
    for (; i < n4; i += stride) {
        float4 v = ((const float4*)in)[i];
        ushort4 o;
        o.x = f2b(v.x); o.y = f2b(v.y); o.z = f2b(v.z); o.w = f2b(v.w);
        ((ushort4*)out)[i] = o;
    }
}

// ---------------------------------------------------------------------------
// x-projection GEMM (bf16 MFMA): X[M=b*S+s][I] @ W_ih^T + biases.
// Output layout: xp[s][cb(64)][b(64)][g*16+cc] -- per (s,colblock) slab is
// contiguous (64 rows x 128B), so the recurrence reads coalesced lines.
// ---------------------------------------------------------------------------
__global__ __launch_bounds__(256) void xproj_mfma(
    const ushort* __restrict__ Xb, const ushort* __restrict__ Wb,
    const float* __restrict__ bih, const float* __restrict__ bhh,
    ushort* __restrict__ xp)
{
    __shared__ ushort As[128][40];
    __shared__ ushort Bs[128][40];
    const int tid  = threadIdx.x;
    const int lane = tid & 63;
    const int w    = tid >> 6;
    const int wm   = (w >> 1) * 64, wn = (w & 1) * 64;
    const int m0   = blockIdx.y * 128, n0 = blockIdx.x * 128;

    const int srow   = tid >> 2;
    const int schunk = (tid & 3) * 8;

    const ushort* Xr0 = Xb + (size_t)(m0 + srow) * I_ + schunk;
    const ushort* Xr1 = Xb + (size_t)(m0 + srow + 64) * I_ + schunk;
    const ushort* Wr0 = Wb + (size_t)(n0 + srow) * I_ + schunk;
    const ushort* Wr1 = Wb + (size_t)(n0 + srow + 64) * I_ + schunk;

    f32x4 acc[4][4];
#pragma unroll
    for (int mi = 0; mi < 4; ++mi)
#pragma unroll
        for (int ni = 0; ni < 4; ++ni)
#pragma unroll
            for (int r = 0; r < 4; ++r) acc[mi][ni][r] = 0.f;

    bf16x8 ra0 = *(const bf16x8*)Xr0;
    bf16x8 ra1 = *(const bf16x8*)Xr1;
    bf16x8 rb0 = *(const bf16x8*)Wr0;
    bf16x8 rb1 = *(const bf16x8*)Wr1;

    const int arow = lane & 15;
    const int akg  = (lane >> 4) * 8;

    for (int kt = 0; kt < 32; ++kt) {
        __syncthreads();
        *(bf16x8*)&As[srow][schunk]      = ra0;
        *(bf16x8*)&As[srow + 64][schunk] = ra1;
        *(bf16x8*)&Bs[srow][schunk]      = rb0;
        *(bf16x8*)&Bs[srow + 64][schunk] = rb1;
        __syncthreads();
        if (kt < 31) {
            int k0 = (kt + 1) * 32;
            ra0 = *(const bf16x8*)(Xr0 + k0);
            ra1 = *(const bf16x8*)(Xr1 + k0);
            rb0 = *(const bf16x8*)(Wr0 + k0);
            rb1 = *(const bf16x8*)(Wr1 + k0);
        }
        bf16x8 af[4], bfv[4];
#pragma unroll
        for (int mi = 0; mi < 4; ++mi)
            af[mi] = *(const bf16x8*)&As[wm + mi * 16 + arow][akg];
#pragma unroll
        for (int ni = 0; ni < 4; ++ni)
            bfv[ni] = *(const bf16x8*)&Bs[wn + ni * 16 + arow][akg];
#pragma unroll
        for (int mi = 0; mi < 4; ++mi)
#pragma unroll
            for (int ni = 0; ni < 4; ++ni)
                acc[mi][ni] = __builtin_amdgcn_mfma_f32_16x16x32_bf16(
                    af[mi], bfv[ni], acc[mi][ni], 0, 0, 0);
    }

    float bsum[4];
#pragma unroll
    for (int ni = 0; ni < 4; ++ni) {
        int col = n0 + wn + ni * 16 + (lane & 15);
        bsum[ni] = bih[col] + bhh[col];
    }
#pragma unroll
    for (int mi = 0; mi < 4; ++mi)
#pragma unroll
        for (int ni = 0; ni < 4; ++ni) {
            int col = n0 + wn + ni * 16 + (lane & 15);  // 0..4095
            int g = col >> 10, hc = col & 1023;
            int cb = hc >> 4, cc = hc & 15;
#pragma unroll
            for (int r = 0; r < 4; ++r) {
                int row = m0 + wm + mi * 16 + (lane >> 4) * 4 + r;  // = b*S + s
                int bb = row >> 9, ss = row & 511;
                xp[(((size_t)ss * 64 + cb) * 64 + bb) * 64 + g * 16 + cc] =
                    f2b(acc[mi][ni][r] + bsum[ni]);
            }
        }
}

// ---------------------------------------------------------------------------
// Persistent LSTM recurrence, fence-free exchange:
//  - h_all[s] is a fresh buffer per step -> consumer L2s can never be stale,
//    so NO acquire fence / L2 invalidate is needed.
//  - h and hseq stores are relaxed agent-scope atomics (sc1, write-through
//    past L2 to the coherence point) -> nothing dirty, release is ~free,
//    no RFO false sharing.
//  - barrier: one release fetch_add per block + relaxed polling.
// ---------------------------------------------------------------------------
__global__ __launch_bounds__(256, 1) void lstm_persist(
    const ushort* __restrict__ Whhb, const ushort* __restrict__ xp,
    ushort* h_all, float* __restrict__ hseq,
    float* __restrict__ hlast, float* __restrict__ clast,
    int* cnt)
{
    __shared__ ushort Ws[64 * WPAD];  // 132096 B

    const int tid  = threadIdx.x;
    const int lane = tid & 63;
    const int w    = tid >> 6;
    const int c0   = blockIdx.x * 16;
    const int l15  = lane & 15;
    const int kg   = lane >> 4;
    const int m0   = w * 16;

    // Load W slice: LDS row r = g*16+cc  <-  Whh row g*1024 + c0 + cc
#pragma unroll
    for (int i = 0; i < 32; ++i) {
        int id = tid + 256 * i;
        int r  = id >> 7;
        int k8 = (id & 127) * 8;
        int g = r >> 4, cc = r & 15;
        *(bf16x8*)&Ws[r * WPAD + k8] =
            *(const bf16x8*)(Whhb + (size_t)(g * H_ + c0 + cc) * H_ + k8);
    }

    float creg[4] = {0.f, 0.f, 0.f, 0.f};
    __syncthreads();

    for (int s = 0; s < S_; ++s) {
        const ushort* hp = h_all + (size_t)s * (B_ * H_);
        ushort*       hn = h_all + (size_t)(s + 1) * (B_ * H_);

        // xp for this step: contiguous slab [s][cb][.][.]
        const ushort* xps = xp + ((size_t)s * 64 + blockIdx.x) * (64 * 64);
        ushort xu[4][4];
#pragma unroll
        for (int r = 0; r < 4; ++r)
#pragma unroll
            for (int g = 0; g < 4; ++g)
                xu[r][g] = xps[(size_t)(m0 + kg * 4 + r) * 64 + g * 16 + l15];

        // A fragments: h rows m0+l15, full K (fresh lines -> L2 miss -> LLC)
        const ushort* Ap = hp + (size_t)(m0 + l15) * H_ + kg * 8;
        bf16x8 a[32];
#pragma unroll
        for (int u = 0; u < 32; ++u) a[u] = *(const bf16x8*)(Ap + u * 32);

        f32x4 ac0, ac1, ac2, ac3;
#pragma unroll
        for (int r = 0; r < 4; ++r) { ac0[r] = 0.f; ac1[r] = 0.f; ac2[r] = 0.f; ac3[r] = 0.f; }

#pragma unroll
        for (int u = 0; u < 32; ++u) {
            const ushort* wp = &Ws[l15 * WPAD + u * 32 + kg * 8];
            bf16x8 b0 = *(const bf16x8*)(wp);
            bf16x8 b1 = *(const bf16x8*)(wp + 16 * WPAD);
            bf16x8 b2 = *(const bf16x8*)(wp + 32 * WPAD);
            bf16x8 b3 = *(const bf16x8*)(wp + 48 * WPAD);
            ac0 = __builtin_amdgcn_mfma_f32_16x16x32_bf16(a[u], b0, ac0, 0, 0, 0);
            ac1 = __builtin_amdgcn_mfma_f32_16x16x32_bf16(a[u], b1, ac1, 0, 0, 0);
            ac2 = __builtin_amdgcn_mfma_f32_16x16x32_bf16(a[u], b2, ac2, 0, 0, 0);
            ac3 = __builtin_amdgcn_mfma_f32_16x16x32_bf16(a[u], b3, ac3, 0, 0, 0);
        }

        // lane-local epilogue; pack col-pairs via shfl, write-through stores
#pragma unroll
        for (int r = 0; r < 4; ++r) {
            int bb = m0 + kg * 4 + r;
            float gi = ac0[r] + b2f(xu[r][0]);
            float gf = ac1[r] + b2f(xu[r][1]);
            float gg = ac2[r] + b2f(xu[r][2]);
            float go = ac3[r] + b2f(xu[r][3]);
            float ii = 1.f / (1.f + __expf(-gi));
            float ff = 1.f / (1.f + __expf(-gf));
            float gt = 1.f - 2.f / (__expf(2.f * gg) + 1.f);
            float oo = 1.f / (1.f + __expf(-go));
            float cn = ff * creg[r] + ii * gt;
            float hv = oo * (1.f - 2.f / (__expf(2.f * cn) + 1.f));
            creg[r] = cn;

            unsigned hb = (unsigned)f2b(hv);
            unsigned hbp = __shfl_xor(hb, 1);
            unsigned fo = __float_as_uint(hv);
            unsigned fp = __shfl_xor(fo, 1);
            if ((l15 & 1) == 0) {
                unsigned hw = hb | (hbp << 16);
                __hip_atomic_store((unsigned*)(hn + (size_t)bb * H_ + c0 + l15), hw,
                                   __ATOMIC_RELAXED, __HIP_MEMORY_SCOPE_AGENT);
                unsigned long long fw = (unsigned long long)fo |
                                        ((unsigned long long)fp << 32);
                __hip_atomic_store((unsigned long long*)
                                       (hseq + ((size_t)bb * S_ + s) * H_ + c0 + l15),
                                   fw, __ATOMIC_RELAXED, __HIP_MEMORY_SCOPE_AGENT);
            }
            if (s == S_ - 1) {
                hlast[(size_t)bb * H_ + c0 + l15] = hv;
                clast[(size_t)bb * H_ + c0 + l15] = cn;
            }
        }

        // grid barrier: release add + relaxed poll (no fences, no L2 inv)
        if (s < S_ - 1) {
            __syncthreads();  // all waves drained vmcnt -> h at coherence point
            if (tid == 0) {
                __hip_atomic_fetch_add(cnt, 1, __ATOMIC_RELEASE,
                                       __HIP_MEMORY_SCOPE_AGENT);
                int target = NB * (s + 1);
                while (__hip_atomic_load(cnt, __ATOMIC_RELAXED,
                                         __HIP_MEMORY_SCOPE_AGENT) < target)
                    __builtin_amdgcn_s_sleep(1);
            }
            __syncthreads();
        }
    }
}

extern "C" void kernel_launch(void* const* d_in, const int* in_sizes, int n_in,
                              void* d_out, int out_size, void* d_ws, size_t ws_size,
                              hipStream_t stream) {
    const float* x   = (const float*)d_in[0];
    const float* Wih = (const float*)d_in[1];
    const float* Whh = (const float*)d_in[2];
    const float* bih = (const float*)d_in[3];
    const float* bhh = (const float*)d_in[4];
    float* out = (float*)d_out;

    // workspace layout (ushort elems)
    ushort* xp    = (ushort*)d_ws;            // 134217728 (268 MB) [s][cb][b][64]
    ushort* xbf   = xp + 134217728;           // 33554432
    ushort* wihb  = xbf + 33554432;           // 4194304
    ushort* whhb  = wihb + 4194304;           // 4194304
    ushort* h_all = whhb + 4194304;           // 513 * 65536 = 33619968 (67 MB)
    int*    cnt   = (int*)(h_all + 33619968);

    float* hseq  = out;
    float* hlast = out + (size_t)B_ * S_ * H_;
    float* clast = hlast + (size_t)B_ * H_;

    hipMemsetAsync(h_all, 0, (size_t)B_ * H_ * sizeof(ushort), stream);  // h_0 = 0
    hipMemsetAsync(cnt, 0, 64, stream);

    conv_f2b_kernel<<<2048, 256, 0, stream>>>(x, xbf, (B_ * S_ * I_) / 4);
    conv_f2b_kernel<<<1024, 256, 0, stream>>>(Wih, wihb, (G_ * I_) / 4);
    conv_f2b_kernel<<<1024, 256, 0, stream>>>(Whh, whhb, (G_ * H_) / 4);

    dim3 gg(G_ / 128, (B_ * S_) / 128);
    xproj_mfma<<<gg, 256, 0, stream>>>(xbf, wihb, bih, bhh, xp);

    lstm_persist<<<NB, 256, 0, stream>>>(whhb, xp, h_all, hseq, hlast, clast, cnt);
}

// Round 5
// 5547.485 us; speedup vs baseline: 1.2433x; 1.0464x over previous
//
#include <hip/hip_runtime.h>

#define B_ 64
#define S_ 512
#define I_ 1024
#define H_ 1024
#define G_ 4096   // 4*H
#define NB 64     // persistent blocks
#define WPAD 1032 // LDS row stride in ushort

typedef __attribute__((ext_vector_type(4))) float f32x4;
typedef __attribute__((ext_vector_type(8))) short bf16x8;

static __device__ __forceinline__ ushort f2b(float f) {
    union { float f; unsigned u; } v; v.f = f;
    unsigned u = v.u;
    unsigned r = (u + 0x7fffu + ((u >> 16) & 1u)) >> 16;
    return (ushort)r;
}
static __device__ __forceinline__ float b2f(ushort b) {
    union { unsigned u; float f; } v; v.u = ((unsigned)b) << 16; return v.f;
}

// ---------------------------------------------------------------------------
// fp32 -> bf16 conversion, vectorized
// ---------------------------------------------------------------------------
__global__ __launch_bounds__(256) void conv_f2b_kernel(
    const float* __restrict__ in, ushort* __restrict__ out, int n4)
{
    int i = blockIdx.x * blockDim.x + threadIdx.x;
    int stride = gridDim.x * blockDim.x;
    for (; i < n4; i += stride) {
        float4 v = ((const float4*)in)[i];
        ushort4 o;
        o.x = f2b(v.x); o.y = f2b(v.y); o.z = f2b(v.z); o.w = f2b(v.w);
        ((ushort4*)out)[i] = o;
    }
}

// ---------------------------------------------------------------------------
// x-projection GEMM (bf16 MFMA): X[M=b*S+s][I] @ W_ih^T + biases.
// Output layout: xp[s][cb(64)][b(64)][g*16+cc] -- per (s,colblock) slab is
// contiguous, so the recurrence reads coalesced lines.
// ---------------------------------------------------------------------------
__global__ __launch_bounds__(256) void xproj_mfma(
    const ushort* __restrict__ Xb, const ushort* __restrict__ Wb,
    const float* __restrict__ bih, const float* __restrict__ bhh,
    ushort* __restrict__ xp)
{
    __shared__ ushort As[128][40];
    __shared__ ushort Bs[128][40];
    const int tid  = threadIdx.x;
    const int lane = tid & 63;
    const int w    = tid >> 6;
    const int wm   = (w >> 1) * 64, wn = (w & 1) * 64;
    const int m0   = blockIdx.y * 128, n0 = blockIdx.x * 128;

    const int srow   = tid >> 2;
    const int schunk = (tid & 3) * 8;

    const ushort* Xr0 = Xb + (size_t)(m0 + srow) * I_ + schunk;
    const ushort* Xr1 = Xb + (size_t)(m0 + srow + 64) * I_ + schunk;
    const ushort* Wr0 = Wb + (size_t)(n0 + srow) * I_ + schunk;
    const ushort* Wr1 = Wb + (size_t)(n0 + srow + 64) * I_ + schunk;

    f32x4 acc[4][4];
#pragma unroll
    for (int mi = 0; mi < 4; ++mi)
#pragma unroll
        for (int ni = 0; ni < 4; ++ni)
#pragma unroll
            for (int r = 0; r < 4; ++r) acc[mi][ni][r] = 0.f;

    bf16x8 ra0 = *(const bf16x8*)Xr0;
    bf16x8 ra1 = *(const bf16x8*)Xr1;
    bf16x8 rb0 = *(const bf16x8*)Wr0;
    bf16x8 rb1 = *(const bf16x8*)Wr1;

    const int arow = lane & 15;
    const int akg  = (lane >> 4) * 8;

    for (int kt = 0; kt < 32; ++kt) {
        __syncthreads();
        *(bf16x8*)&As[srow][schunk]      = ra0;
        *(bf16x8*)&As[srow + 64][schunk] = ra1;
        *(bf16x8*)&Bs[srow][schunk]      = rb0;
        *(bf16x8*)&Bs[srow + 64][schunk] = rb1;
        __syncthreads();
        if (kt < 31) {
            int k0 = (kt + 1) * 32;
            ra0 = *(const bf16x8*)(Xr0 + k0);
            ra1 = *(const bf16x8*)(Xr1 + k0);
            rb0 = *(const bf16x8*)(Wr0 + k0);
            rb1 = *(const bf16x8*)(Wr1 + k0);
        }
        bf16x8 af[4], bfv[4];
#pragma unroll
        for (int mi = 0; mi < 4; ++mi)
            af[mi] = *(const bf16x8*)&As[wm + mi * 16 + arow][akg];
#pragma unroll
        for (int ni = 0; ni < 4; ++ni)
            bfv[ni] = *(const bf16x8*)&Bs[wn + ni * 16 + arow][akg];
#pragma unroll
        for (int mi = 0; mi < 4; ++mi)
#pragma unroll
            for (int ni = 0; ni < 4; ++ni)
                acc[mi][ni] = __builtin_amdgcn_mfma_f32_16x16x32_bf16(
                    af[mi], bfv[ni], acc[mi][ni], 0, 0, 0);
    }

    float bsum[4];
#pragma unroll
    for (int ni = 0; ni < 4; ++ni) {
        int col = n0 + wn + ni * 16 + (lane & 15);
        bsum[ni] = bih[col] + bhh[col];
    }
#pragma unroll
    for (int mi = 0; mi < 4; ++mi)
#pragma unroll
        for (int ni = 0; ni < 4; ++ni) {
            int col = n0 + wn + ni * 16 + (lane & 15);  // 0..4095
            int g = col >> 10, hc = col & 1023;
            int cb = hc >> 4, cc = hc & 15;
#pragma unroll
            for (int r = 0; r < 4; ++r) {
                int row = m0 + wm + mi * 16 + (lane >> 4) * 4 + r;  // = b*S + s
                int bb = row >> 9, ss = row & 511;
                xp[(((size_t)ss * 64 + cb) * 64 + bb) * 64 + g * 16 + cc] =
                    f2b(acc[mi][ni][r] + bsum[ni]);
            }
        }
}

// ---------------------------------------------------------------------------
// Persistent LSTM recurrence with wave<->wave dataflow flags (no global
// barrier). flags[s][w][j] = "block j, wave w, has written its 16-col chunk
// of h_all[s]". Producer: sc1 h-stores -> vmcnt(0) -> flag. Consumer wave w:
// single 64-lane atomic load polls all 64 flags, ballot until complete, then
// bulk A-loads. Blocks drift <=1 step; no fences, no L2 invalidates.
// ---------------------------------------------------------------------------
__global__ __launch_bounds__(256, 1) void lstm_persist(
    const ushort* __restrict__ Whhb, const ushort* __restrict__ xp,
    ushort* h_all, int* flags, float* __restrict__ hseq,
    float* __restrict__ hlast, float* __restrict__ clast)
{
    __shared__ ushort Ws[64 * WPAD];  // 132096 B

    const int tid  = threadIdx.x;
    const int lane = tid & 63;
    const int w    = tid >> 6;
    const int c0   = blockIdx.x * 16;
    const int l15  = lane & 15;
    const int kg   = lane >> 4;
    const int m0   = w * 16;

    // Load W slice: LDS row r = g*16+cc  <-  Whh row g*1024 + c0 + cc
#pragma unroll
    for (int i = 0; i < 32; ++i) {
        int id = tid + 256 * i;
        int r  = id >> 7;
        int k8 = (id & 127) * 8;
        int g = r >> 4, cc = r & 15;
        *(bf16x8*)&Ws[r * WPAD + k8] =
            *(const bf16x8*)(Whhb + (size_t)(g * H_ + c0 + cc) * H_ + k8);
    }

    float creg[4] = {0.f, 0.f, 0.f, 0.f};
    __syncthreads();

    for (int s = 0; s < S_; ++s) {
        const ushort* hp = h_all + (size_t)s * (B_ * H_);
        ushort*       hn = h_all + (size_t)(s + 1) * (B_ * H_);

        // xp for this step: contiguous slab [s][cb][.][.] -- issue before poll
        const ushort* xps = xp + ((size_t)s * 64 + blockIdx.x) * (64 * 64);
        ushort xu[4][4];
#pragma unroll
        for (int r = 0; r < 4; ++r)
#pragma unroll
            for (int g = 0; g < 4; ++g)
                xu[r][g] = xps[(size_t)(m0 + kg * 4 + r) * 64 + g * 16 + l15];

        // Dataflow wait: all 64 producer chunks of this wave's batch rows
        if (s > 0) {
            int* fp = flags + ((size_t)s * 4 + w) * 64 + lane;
            unsigned long long rdy;
            do {
                int f = __hip_atomic_load(fp, __ATOMIC_RELAXED,
                                          __HIP_MEMORY_SCOPE_AGENT);
                rdy = __ballot(f != 0);
            } while (rdy != ~0ULL);
            asm volatile("" ::: "memory");  // pin A-loads after flag check
        }

        // A fragments: h rows m0+l15, full K
        const ushort* Ap = hp + (size_t)(m0 + l15) * H_ + kg * 8;
        bf16x8 a[32];
#pragma unroll
        for (int u = 0; u < 32; ++u) a[u] = *(const bf16x8*)(Ap + u * 32);

        f32x4 ac0, ac1, ac2, ac3;
#pragma unroll
        for (int r = 0; r < 4; ++r) { ac0[r] = 0.f; ac1[r] = 0.f; ac2[r] = 0.f; ac3[r] = 0.f; }

#pragma unroll
        for (int u = 0; u < 32; ++u) {
            const ushort* wp = &Ws[l15 * WPAD + u * 32 + kg * 8];
            bf16x8 b0 = *(const bf16x8*)(wp);
            bf16x8 b1 = *(const bf16x8*)(wp + 16 * WPAD);
            bf16x8 b2 = *(const bf16x8*)(wp + 32 * WPAD);
            bf16x8 b3 = *(const bf16x8*)(wp + 48 * WPAD);
            ac0 = __builtin_amdgcn_mfma_f32_16x16x32_bf16(a[u], b0, ac0, 0, 0, 0);
            ac1 = __builtin_amdgcn_mfma_f32_16x16x32_bf16(a[u], b1, ac1, 0, 0, 0);
            ac2 = __builtin_amdgcn_mfma_f32_16x16x32_bf16(a[u], b2, ac2, 0, 0, 0);
            ac3 = __builtin_amdgcn_mfma_f32_16x16x32_bf16(a[u], b3, ac3, 0, 0, 0);
        }

        // lane-local epilogue
        float hv[4], cn[4];
#pragma unroll
        for (int r = 0; r < 4; ++r) {
            float gi = ac0[r] + b2f(xu[r][0]);
            float gf = ac1[r] + b2f(xu[r][1]);
            float gg = ac2[r] + b2f(xu[r][2]);
            float go = ac3[r] + b2f(xu[r][3]);
            float ii = 1.f / (1.f + __expf(-gi));
            float ff = 1.f / (1.f + __expf(-gf));
            float gt = 1.f - 2.f / (__expf(2.f * gg) + 1.f);
            float oo = 1.f / (1.f + __expf(-go));
            cn[r] = ff * creg[r] + ii * gt;
            hv[r] = oo * (1.f - 2.f / (__expf(2.f * cn[r]) + 1.f));
            creg[r] = cn[r];
        }

        // h stores (write-through, packed pairs) -> drain -> flag
#pragma unroll
        for (int r = 0; r < 4; ++r) {
            int bb = m0 + kg * 4 + r;
            unsigned hb = (unsigned)f2b(hv[r]);
            unsigned hpp = __shfl_xor(hb, 1);
            if ((l15 & 1) == 0) {
                unsigned hw = hb | (hpp << 16);
                __hip_atomic_store((unsigned*)(hn + (size_t)bb * H_ + c0 + l15), hw,
                                   __ATOMIC_RELAXED, __HIP_MEMORY_SCOPE_AGENT);
            }
        }
        asm volatile("s_waitcnt vmcnt(0)" ::: "memory");
        if (s < S_ - 1 && lane == 0) {
            __hip_atomic_store(flags + ((size_t)(s + 1) * 4 + w) * 64 + blockIdx.x,
                               1, __ATOMIC_RELAXED, __HIP_MEMORY_SCOPE_AGENT);
        }

        // hseq (and final h/c) stores off the critical path
#pragma unroll
        for (int r = 0; r < 4; ++r) {
            int bb = m0 + kg * 4 + r;
            unsigned fo = __float_as_uint(hv[r]);
            unsigned fp2 = __shfl_xor(fo, 1);
            if ((l15 & 1) == 0) {
                unsigned long long fw = (unsigned long long)fo |
                                        ((unsigned long long)fp2 << 32);
                __hip_atomic_store((unsigned long long*)
                                       (hseq + ((size_t)bb * S_ + s) * H_ + c0 + l15),
                                   fw, __ATOMIC_RELAXED, __HIP_MEMORY_SCOPE_AGENT);
            }
            if (s == S_ - 1) {
                hlast[(size_t)bb * H_ + c0 + l15] = hv[r];
                clast[(size_t)bb * H_ + c0 + l15] = cn[r];
            }
        }
    }
}

extern "C" void kernel_launch(void* const* d_in, const int* in_sizes, int n_in,
                              void* d_out, int out_size, void* d_ws, size_t ws_size,
                              hipStream_t stream) {
    const float* x   = (const float*)d_in[0];
    const float* Wih = (const float*)d_in[1];
    const float* Whh = (const float*)d_in[2];
    const float* bih = (const float*)d_in[3];
    const float* bhh = (const float*)d_in[4];
    float* out = (float*)d_out;

    // workspace layout (ushort elems)
    ushort* xp    = (ushort*)d_ws;            // 134217728 (268 MB) [s][cb][b][64]
    ushort* xbf   = xp + 134217728;           // 33554432
    ushort* wihb  = xbf + 33554432;           // 4194304
    ushort* whhb  = wihb + 4194304;           // 4194304
    ushort* h_all = whhb + 4194304;           // 513 * 65536 ushorts (67 MB)
    int*    flags = (int*)(h_all + 33619968); // 512*4*64 ints = 512 KB

    float* hseq  = out;
    float* hlast = out + (size_t)B_ * S_ * H_;
    float* clast = hlast + (size_t)B_ * H_;

    hipMemsetAsync(h_all, 0, (size_t)B_ * H_ * sizeof(ushort), stream);  // h_0 = 0
    hipMemsetAsync(flags, 0, (size_t)S_ * 4 * 64 * sizeof(int), stream);

    conv_f2b_kernel<<<2048, 256, 0, stream>>>(x, xbf, (B_ * S_ * I_) / 4);
    conv_f2b_kernel<<<1024, 256, 0, stream>>>(Wih, wihb, (G_ * I_) / 4);
    conv_f2b_kernel<<<1024, 256, 0, stream>>>(Whh, whhb, (G_ * H_) / 4);

    dim3 gg(G_ / 128, (B_ * S_) / 128);
    xproj_mfma<<<gg, 256, 0, stream>>>(xbf, wihb, bih, bhh, xp);

    lstm_persist<<<NB, 256, 0, stream>>>(whhb, xp, h_all, flags,
                                         hseq, hlast, clast);
}